// Round 1
// baseline (962.134 us; speedup 1.0000x reference)
//
#include <hip/hip_runtime.h>

// LightGCN propagation: 3 layers of y = G@x (scatter-add over 1.2M edges),
// blend emb = 0.2*emb + 0.8*y, acc += emb, then 4096 gathered dot products.
//
// Constants from the reference:
#define NUM_USERS 100000
#define NUM_ITEMS 50000
#define N_NODES   150000
#define DIM       64
#define N_EDGES   1200000
#define ND        (N_NODES * DIM)   // 9,600,000 floats

// ---------------------------------------------------------------------------
// init: emb = acc = concat(user_emb, item_emb), vectorized float4
// ---------------------------------------------------------------------------
__global__ void init_kernel(const float* __restrict__ ue,
                            const float* __restrict__ ie,
                            float* __restrict__ emb,
                            float* __restrict__ acc) {
    const int n4  = ND / 4;                 // 2,400,000
    const int nu4 = NUM_USERS * DIM / 4;    // 1,600,000
    int i = blockIdx.x * blockDim.x + threadIdx.x;
    int stride = gridDim.x * blockDim.x;
    for (; i < n4; i += stride) {
        float4 v = (i < nu4) ? ((const float4*)ue)[i]
                             : ((const float4*)ie)[i - nu4];
        ((float4*)emb)[i] = v;
        ((float4*)acc)[i] = v;
    }
}

// ---------------------------------------------------------------------------
// spmm: one wave per edge, lane d handles dimension d.
//   y[row*64 + d] += val * x[col*64 + d]   (float atomics)
// ---------------------------------------------------------------------------
__global__ void spmm_kernel(const int* __restrict__ row,
                            const int* __restrict__ col,
                            const float* __restrict__ val,
                            const float* __restrict__ x,
                            float* __restrict__ y) {
    int wave   = (blockIdx.x * blockDim.x + threadIdx.x) >> 6;
    int lane   = threadIdx.x & 63;
    int nwaves = (gridDim.x * blockDim.x) >> 6;
    for (int e = wave; e < N_EDGES; e += nwaves) {
        int   r = row[e];
        int   c = col[e];
        float v = val[e];
        float xv = x[c * DIM + lane];        // coalesced 256B wave read
        atomicAdd(&y[r * DIM + lane], v * xv);
    }
}

// ---------------------------------------------------------------------------
// combine: emb = 0.2*emb + 0.8*y;  acc += emb   (vectorized)
// ---------------------------------------------------------------------------
__global__ void combine_kernel(float* __restrict__ emb,
                               const float* __restrict__ y,
                               float* __restrict__ acc) {
    const int n4 = ND / 4;
    int i = blockIdx.x * blockDim.x + threadIdx.x;
    int stride = gridDim.x * blockDim.x;
    for (; i < n4; i += stride) {
        float4 e  = ((float4*)emb)[i];
        float4 yy = ((const float4*)y)[i];
        float4 a  = ((float4*)acc)[i];
        e.x = 0.2f * e.x + 0.8f * yy.x;
        e.y = 0.2f * e.y + 0.8f * yy.y;
        e.z = 0.2f * e.z + 0.8f * yy.z;
        e.w = 0.2f * e.w + 0.8f * yy.w;
        a.x += e.x; a.y += e.y; a.z += e.z; a.w += e.w;
        ((float4*)emb)[i] = e;
        ((float4*)acc)[i] = a;
    }
}

// ---------------------------------------------------------------------------
// epilogue: out[b] = dot(acc[users[b]], acc[NUM_USERS+items[b]]) / 16
//   (light_out = acc/4 for both operands -> /16 on the dot)
//   one wave per output element, shuffle reduction over 64 lanes
// ---------------------------------------------------------------------------
__global__ void dot_kernel(const int* __restrict__ users,
                           const int* __restrict__ items,
                           const float* __restrict__ acc,
                           float* __restrict__ out,
                           int nb) {
    int wave = (blockIdx.x * blockDim.x + threadIdx.x) >> 6;
    int lane = threadIdx.x & 63;
    if (wave >= nb) return;
    int u  = users[wave];
    int it = items[wave];
    float p = acc[u * DIM + lane] * acc[(NUM_USERS + it) * DIM + lane];
    #pragma unroll
    for (int o = 32; o > 0; o >>= 1) p += __shfl_down(p, o, 64);
    if (lane == 0) out[wave] = p * (1.0f / 16.0f);
}

// ---------------------------------------------------------------------------
extern "C" void kernel_launch(void* const* d_in, const int* in_sizes, int n_in,
                              void* d_out, int out_size, void* d_ws, size_t ws_size,
                              hipStream_t stream) {
    const int*   users = (const int*)  d_in[0];
    const int*   items = (const int*)  d_in[1];
    const int*   erow  = (const int*)  d_in[2];
    const int*   ecol  = (const int*)  d_in[3];
    const float* evalv = (const float*)d_in[4];
    const float* ue    = (const float*)d_in[5];
    const float* ie    = (const float*)d_in[6];
    float* out = (float*)d_out;

    // workspace layout: emb | y | acc   (3 x 38.4 MB)
    float* emb = (float*)d_ws;
    float* y   = emb + ND;
    float* acc = y + ND;

    const int block = 256;
    const int grid_elem = (ND / 4 + block - 1) / block;   // 9375 blocks

    init_kernel<<<grid_elem, block, 0, stream>>>(ue, ie, emb, acc);

    for (int l = 0; l < 3; ++l) {
        hipMemsetAsync(y, 0, (size_t)ND * sizeof(float), stream);
        // 4096 blocks * 4 waves = 16384 waves, ~74 edges each (grid-stride)
        spmm_kernel<<<4096, block, 0, stream>>>(erow, ecol, evalv, emb, y);
        combine_kernel<<<grid_elem, block, 0, stream>>>(emb, y, acc);
    }

    const int nb = out_size;                       // 4096
    dot_kernel<<<(nb * 64 + block - 1) / block, block, 0, stream>>>(
        users, items, acc, out, nb);
}

// Round 2
// 478.749 us; speedup vs baseline: 2.0097x; 2.0097x over previous
//
#include <hip/hip_runtime.h>

// LightGCN propagation, CSR formulation (no atomics in the hot loop).
// Per call: build CSR (hist -> 2-level scan -> fill), then 3x fused
// spmm+blend layers with ping-pong emb buffers; acc maintained only at
// the 8192 sampled rows (2 MB) instead of all 150K rows.

#define NUM_USERS 100000
#define NUM_ITEMS 50000
#define N_NODES   150000
#define DIM       64
#define N_EDGES   1200000
#define ND        (N_NODES * DIM)   // 9,600,000 floats
#define NB        4096              // batch size
#define NSAMP     (2 * NB)          // 8192 sampled rows

// ---------------------------------------------------------------------------
// init: emb = concat(user_emb, item_emb), vectorized float4
// ---------------------------------------------------------------------------
__global__ void init_kernel(const float* __restrict__ ue,
                            const float* __restrict__ ie,
                            float* __restrict__ emb) {
    const int n4  = ND / 4;
    const int nu4 = NUM_USERS * DIM / 4;
    int i = blockIdx.x * blockDim.x + threadIdx.x;
    int stride = gridDim.x * blockDim.x;
    for (; i < n4; i += stride) {
        float4 v = (i < nu4) ? ((const float4*)ue)[i]
                             : ((const float4*)ie)[i - nu4];
        ((float4*)emb)[i] = v;
    }
}

// ---------------------------------------------------------------------------
// CSR build step 1: histogram of row ids (atomics on 600KB, L2-resident)
// ---------------------------------------------------------------------------
__global__ void hist_kernel(const int* __restrict__ row, int* __restrict__ counts) {
    int i = blockIdx.x * blockDim.x + threadIdx.x;
    int stride = gridDim.x * blockDim.x;
    for (; i < N_EDGES; i += stride)
        atomicAdd(&counts[row[i]], 1);
}

// ---------------------------------------------------------------------------
// CSR build step 2a: per-block exclusive scan (256-wide) + block sums
// ---------------------------------------------------------------------------
__global__ void scan_block_kernel(const int* __restrict__ counts,
                                  int* __restrict__ offsets,
                                  int* __restrict__ blocksums, int n) {
    __shared__ int tmp[256];
    int tid = threadIdx.x;
    int i = blockIdx.x * 256 + tid;
    int v = (i < n) ? counts[i] : 0;
    tmp[tid] = v;
    __syncthreads();
    #pragma unroll
    for (int o = 1; o < 256; o <<= 1) {
        int t = (tid >= o) ? tmp[tid - o] : 0;
        __syncthreads();
        tmp[tid] += t;
        __syncthreads();
    }
    if (i < n) offsets[i] = tmp[tid] - v;   // exclusive
    if (tid == 255) blocksums[blockIdx.x] = tmp[255];
}

// ---------------------------------------------------------------------------
// CSR build step 2b: scan the block sums (nb <= 1024) in one block
// ---------------------------------------------------------------------------
__global__ void scan_sums_kernel(int* __restrict__ blocksums, int nb) {
    __shared__ int tmp[1024];
    int tid = threadIdx.x;
    int v = (tid < nb) ? blocksums[tid] : 0;
    tmp[tid] = v;
    __syncthreads();
    #pragma unroll
    for (int o = 1; o < 1024; o <<= 1) {
        int t = (tid >= o) ? tmp[tid - o] : 0;
        __syncthreads();
        tmp[tid] += t;
        __syncthreads();
    }
    if (tid < nb) blocksums[tid] = tmp[tid] - v;  // exclusive
}

// ---------------------------------------------------------------------------
// CSR build step 2c: add block offsets; write sentinel offsets[N]=E
// ---------------------------------------------------------------------------
__global__ void add_offsets_kernel(int* __restrict__ offsets,
                                   const int* __restrict__ blocksums, int n) {
    int i = blockIdx.x * blockDim.x + threadIdx.x;
    if (i < n) offsets[i] += blocksums[i >> 8];
    if (i == 0) offsets[n] = N_EDGES;
}

// ---------------------------------------------------------------------------
// CSR build step 3: scatter edges into row-sorted arrays
// ---------------------------------------------------------------------------
__global__ void fill_kernel(const int* __restrict__ row,
                            const int* __restrict__ col,
                            const float* __restrict__ val,
                            const int* __restrict__ offsets,
                            int* __restrict__ cursor,
                            int* __restrict__ csr_col,
                            float* __restrict__ csr_val) {
    int i = blockIdx.x * blockDim.x + threadIdx.x;
    int stride = gridDim.x * blockDim.x;
    for (; i < N_EDGES; i += stride) {
        int r = row[i];
        int p = offsets[r] + atomicAdd(&cursor[r], 1);
        csr_col[p] = col[i];
        csr_val[p] = val[i];
    }
}

// ---------------------------------------------------------------------------
// fused spmm + blend: one wave per row, lane d = dim d.
//   out[row] = 0.2*x[row] + 0.8 * sum_e val[e]*x[col[e]]
// No atomics; each output row written exactly once.
// ---------------------------------------------------------------------------
__global__ void spmm_kernel(const int* __restrict__ offsets,
                            const int* __restrict__ csr_col,
                            const float* __restrict__ csr_val,
                            const float* __restrict__ x,
                            float* __restrict__ xout) {
    int wrow = blockIdx.x * (blockDim.x >> 6) + (threadIdx.x >> 6);
    int lane = threadIdx.x & 63;
    if (wrow >= N_NODES) return;
    int beg = offsets[wrow];
    int end = offsets[wrow + 1];
    float s0 = 0.f, s1 = 0.f, s2 = 0.f, s3 = 0.f;
    int e = beg;
    for (; e + 4 <= end; e += 4) {
        int   c0 = csr_col[e],     c1 = csr_col[e + 1];
        int   c2 = csr_col[e + 2], c3 = csr_col[e + 3];
        float v0 = csr_val[e],     v1 = csr_val[e + 1];
        float v2 = csr_val[e + 2], v3 = csr_val[e + 3];
        s0 += v0 * x[c0 * DIM + lane];
        s1 += v1 * x[c1 * DIM + lane];
        s2 += v2 * x[c2 * DIM + lane];
        s3 += v3 * x[c3 * DIM + lane];
    }
    for (; e < end; ++e)
        s0 += csr_val[e] * x[csr_col[e] * DIM + lane];
    float sum = (s0 + s1) + (s2 + s3);
    xout[wrow * DIM + lane] = 0.2f * x[wrow * DIM + lane] + 0.8f * sum;
}

// ---------------------------------------------------------------------------
// accumulate current layer's emb at the 8192 sampled rows into acc_small
// ---------------------------------------------------------------------------
__global__ void accum_kernel(const int* __restrict__ users,
                             const int* __restrict__ items,
                             const float* __restrict__ emb,
                             float* __restrict__ acc_small) {
    int w = (blockIdx.x * blockDim.x + threadIdx.x) >> 6;
    int lane = threadIdx.x & 63;
    if (w >= NSAMP) return;
    int node = (w < NB) ? users[w] : (NUM_USERS + items[w - NB]);
    acc_small[w * DIM + lane] += emb[node * DIM + lane];
}

// ---------------------------------------------------------------------------
// out[b] = dot(acc_small[b], acc_small[NB+b]) / 16
// ---------------------------------------------------------------------------
__global__ void dot_kernel(const float* __restrict__ acc_small,
                           float* __restrict__ out) {
    int w = (blockIdx.x * blockDim.x + threadIdx.x) >> 6;
    int lane = threadIdx.x & 63;
    if (w >= NB) return;
    float p = acc_small[w * DIM + lane] * acc_small[(NB + w) * DIM + lane];
    #pragma unroll
    for (int o = 32; o > 0; o >>= 1) p += __shfl_down(p, o, 64);
    if (lane == 0) out[w] = p * (1.0f / 16.0f);
}

// ---------------------------------------------------------------------------
extern "C" void kernel_launch(void* const* d_in, const int* in_sizes, int n_in,
                              void* d_out, int out_size, void* d_ws, size_t ws_size,
                              hipStream_t stream) {
    const int*   users = (const int*)  d_in[0];
    const int*   items = (const int*)  d_in[1];
    const int*   erow  = (const int*)  d_in[2];
    const int*   ecol  = (const int*)  d_in[3];
    const float* evalv = (const float*)d_in[4];
    const float* ue    = (const float*)d_in[5];
    const float* ie    = (const float*)d_in[6];
    float* out = (float*)d_out;

    // workspace layout
    float* emb_a     = (float*)d_ws;            // ND floats
    float* emb_b     = emb_a + ND;              // ND floats
    float* acc_small = emb_b + ND;              // NSAMP*DIM floats (2 MB)
    float* csr_val   = acc_small + NSAMP * DIM; // N_EDGES floats
    int*   csr_col   = (int*)(csr_val + N_EDGES);         // N_EDGES ints
    int*   counts    = csr_col + N_EDGES;                 // N_NODES ints
    int*   offsets   = counts + N_NODES;                  // N_NODES+1 ints
    int*   blocksums = offsets + N_NODES + 1;             // <=1024 ints

    const int block = 256;
    const int nscan_blocks = (N_NODES + 255) / 256;       // 586

    // --- init emb_a + zero acc_small / counts -----------------------------
    init_kernel<<<(ND / 4 + block - 1) / block, block, 0, stream>>>(ue, ie, emb_a);
    hipMemsetAsync(acc_small, 0, (size_t)NSAMP * DIM * sizeof(float), stream);
    hipMemsetAsync(counts, 0, (size_t)N_NODES * sizeof(int), stream);

    // --- build CSR --------------------------------------------------------
    hist_kernel<<<2048, block, 0, stream>>>(erow, counts);
    scan_block_kernel<<<nscan_blocks, 256, 0, stream>>>(counts, offsets, blocksums, N_NODES);
    scan_sums_kernel<<<1, 1024, 0, stream>>>(blocksums, nscan_blocks);
    add_offsets_kernel<<<nscan_blocks, 256, 0, stream>>>(offsets, blocksums, N_NODES);
    hipMemsetAsync(counts, 0, (size_t)N_NODES * sizeof(int), stream);  // reuse as cursor
    fill_kernel<<<2048, block, 0, stream>>>(erow, ecol, evalv, offsets, counts,
                                            csr_col, csr_val);

    // --- layer 0 contribution (emb^0) at sampled rows ---------------------
    accum_kernel<<<(NSAMP * 64 + block - 1) / block, block, 0, stream>>>(
        users, items, emb_a, acc_small);

    // --- 3 propagation layers, ping-pong ----------------------------------
    const int spmm_blocks = (N_NODES + 3) / 4;   // 4 rows (waves) per block
    float* xin  = emb_a;
    float* xout = emb_b;
    for (int l = 0; l < 3; ++l) {
        spmm_kernel<<<spmm_blocks, block, 0, stream>>>(offsets, csr_col, csr_val,
                                                       xin, xout);
        accum_kernel<<<(NSAMP * 64 + block - 1) / block, block, 0, stream>>>(
            users, items, xout, acc_small);
        float* t = xin; xin = xout; xout = t;
    }

    // --- final dot ---------------------------------------------------------
    dot_kernel<<<(NB * 64 + block - 1) / block, block, 0, stream>>>(acc_small, out);
}

// Round 3
// 395.534 us; speedup vs baseline: 2.4325x; 1.2104x over previous
//
#include <hip/hip_runtime.h>

// LightGCN propagation, CSR + frontier pruning.
//  - CSR edges interleaved as int2{col, val_bits}: 1 scattered 8B write/edge.
//  - No init: layer-1 & accum-0 read user/item tables via index translation.
//  - Byte masks prune layer-2 (~63K rows) and layer-3 (~8K rows) spmm.

#define NUM_USERS 100000
#define NUM_ITEMS 50000
#define N_NODES   150000
#define DIM       64
#define N_EDGES   1200000
#define ND        (N_NODES * DIM)
#define NB        4096
#define NSAMP     (2 * NB)

// ---------------------------------------------------------------------------
// translated gather: first layer reads the raw tables, later layers read emb
// ---------------------------------------------------------------------------
__device__ __forceinline__ float gx(const float* __restrict__ x,
                                    const float* __restrict__ ue,
                                    const float* __restrict__ ie,
                                    int node, int lane, bool first) {
    if (first)
        return (node < NUM_USERS) ? ue[node * DIM + lane]
                                  : ie[(node - NUM_USERS) * DIM + lane];
    return x[node * DIM + lane];
}

// ---------------------------------------------------------------------------
// CSR build: histogram (atomics on 600KB, L2-resident)
// ---------------------------------------------------------------------------
__global__ void hist_kernel(const int* __restrict__ row, int* __restrict__ counts) {
    int i = blockIdx.x * blockDim.x + threadIdx.x;
    int stride = gridDim.x * blockDim.x;
    for (; i < N_EDGES; i += stride)
        atomicAdd(&counts[row[i]], 1);
}

// per-block exclusive scan (256-wide) + block sums
__global__ void scan_block_kernel(const int* __restrict__ counts,
                                  int* __restrict__ offsets,
                                  int* __restrict__ blocksums, int n) {
    __shared__ int tmp[256];
    int tid = threadIdx.x;
    int i = blockIdx.x * 256 + tid;
    int v = (i < n) ? counts[i] : 0;
    tmp[tid] = v;
    __syncthreads();
    #pragma unroll
    for (int o = 1; o < 256; o <<= 1) {
        int t = (tid >= o) ? tmp[tid - o] : 0;
        __syncthreads();
        tmp[tid] += t;
        __syncthreads();
    }
    if (i < n) offsets[i] = tmp[tid] - v;   // exclusive
    if (tid == 255) blocksums[blockIdx.x] = tmp[255];
}

__global__ void scan_sums_kernel(int* __restrict__ blocksums, int nb) {
    __shared__ int tmp[1024];
    int tid = threadIdx.x;
    int v = (tid < nb) ? blocksums[tid] : 0;
    tmp[tid] = v;
    __syncthreads();
    #pragma unroll
    for (int o = 1; o < 1024; o <<= 1) {
        int t = (tid >= o) ? tmp[tid - o] : 0;
        __syncthreads();
        tmp[tid] += t;
        __syncthreads();
    }
    if (tid < nb) blocksums[tid] = tmp[tid] - v;
}

__global__ void add_offsets_kernel(int* __restrict__ offsets,
                                   const int* __restrict__ blocksums, int n) {
    int i = blockIdx.x * blockDim.x + threadIdx.x;
    if (i < n) offsets[i] += blocksums[i >> 8];
    if (i == 0) offsets[n] = N_EDGES;
}

// scatter edges into row-sorted int2 array; cursor = counts (degrees),
// consumed via atomicSub so no second memset is needed.
__global__ void fill_kernel(const int* __restrict__ row,
                            const int* __restrict__ col,
                            const float* __restrict__ val,
                            const int* __restrict__ offsets,
                            int* __restrict__ cursor,
                            int2* __restrict__ csr) {
    int i = blockIdx.x * blockDim.x + threadIdx.x;
    int stride = gridDim.x * blockDim.x;
    for (; i < N_EDGES; i += stride) {
        int r = row[i];
        int p = offsets[r] + atomicSub(&cursor[r], 1) - 1;
        csr[p] = make_int2(col[i], __float_as_int(val[i]));
    }
}

// ---------------------------------------------------------------------------
// frontier masks (byte stores of 1 race benignly; arrays are 150KB, L2-hot)
// ---------------------------------------------------------------------------
__global__ void mark_s_kernel(const int* __restrict__ users,
                              const int* __restrict__ items,
                              unsigned char* __restrict__ m) {
    int i = blockIdx.x * blockDim.x + threadIdx.x;
    if (i < NB) m[users[i]] = 1;
    else if (i < NSAMP) m[NUM_USERS + items[i - NB]] = 1;
}

__global__ void copy_mask_kernel(const unsigned char* __restrict__ src,
                                 unsigned char* __restrict__ dst) {
    int i = blockIdx.x * blockDim.x + threadIdx.x;
    if (i < N_NODES) dst[i] = src[i];
}

// if row is needed at the next layer, its cols are needed at this layer
__global__ void expand_kernel(const int* __restrict__ row,
                              const int* __restrict__ col,
                              const unsigned char* __restrict__ mIn,
                              unsigned char* __restrict__ mOut) {
    int i = blockIdx.x * blockDim.x + threadIdx.x;
    int stride = gridDim.x * blockDim.x;
    for (; i < N_EDGES; i += stride)
        if (mIn[row[i]]) mOut[col[i]] = 1;
}

// ---------------------------------------------------------------------------
// fused spmm + blend, masked: one wave per row, lane d = dim d.
//   out[row] = 0.2*x[row] + 0.8 * sum_e val[e]*x[col[e]]
// ---------------------------------------------------------------------------
template<bool FIRST>
__global__ void spmm_kernel(const int* __restrict__ offsets,
                            const int2* __restrict__ csr,
                            const float* __restrict__ x,
                            const float* __restrict__ ue,
                            const float* __restrict__ ie,
                            const unsigned char* __restrict__ mask,
                            float* __restrict__ xout) {
    int wrow = blockIdx.x * (blockDim.x >> 6) + (threadIdx.x >> 6);
    int lane = threadIdx.x & 63;
    if (wrow >= N_NODES) return;
    if (!mask[wrow]) return;
    int beg = offsets[wrow];
    int end = offsets[wrow + 1];
    float s0 = 0.f, s1 = 0.f, s2 = 0.f, s3 = 0.f;
    int e = beg;
    for (; e + 4 <= end; e += 4) {
        int2 e0 = csr[e],     e1 = csr[e + 1];
        int2 e2 = csr[e + 2], e3 = csr[e + 3];
        s0 += __int_as_float(e0.y) * gx(x, ue, ie, e0.x, lane, FIRST);
        s1 += __int_as_float(e1.y) * gx(x, ue, ie, e1.x, lane, FIRST);
        s2 += __int_as_float(e2.y) * gx(x, ue, ie, e2.x, lane, FIRST);
        s3 += __int_as_float(e3.y) * gx(x, ue, ie, e3.x, lane, FIRST);
    }
    for (; e < end; ++e) {
        int2 ee = csr[e];
        s0 += __int_as_float(ee.y) * gx(x, ue, ie, ee.x, lane, FIRST);
    }
    float sum  = (s0 + s1) + (s2 + s3);
    float self = gx(x, ue, ie, wrow, lane, FIRST);
    xout[wrow * DIM + lane] = 0.2f * self + 0.8f * sum;
}

// ---------------------------------------------------------------------------
// accumulate layer emb at the 8192 sampled rows; FIRST stores (no memset)
// ---------------------------------------------------------------------------
template<bool FIRST>
__global__ void accum_kernel(const int* __restrict__ users,
                             const int* __restrict__ items,
                             const float* __restrict__ emb,
                             const float* __restrict__ ue,
                             const float* __restrict__ ie,
                             float* __restrict__ acc_small) {
    int w = (blockIdx.x * blockDim.x + threadIdx.x) >> 6;
    int lane = threadIdx.x & 63;
    if (w >= NSAMP) return;
    int node = (w < NB) ? users[w] : (NUM_USERS + items[w - NB]);
    float v = gx(emb, ue, ie, node, lane, FIRST);
    if (FIRST) acc_small[w * DIM + lane] = v;
    else       acc_small[w * DIM + lane] += v;
}

// ---------------------------------------------------------------------------
__global__ void dot_kernel(const float* __restrict__ acc_small,
                           float* __restrict__ out) {
    int w = (blockIdx.x * blockDim.x + threadIdx.x) >> 6;
    int lane = threadIdx.x & 63;
    if (w >= NB) return;
    float p = acc_small[w * DIM + lane] * acc_small[(NB + w) * DIM + lane];
    #pragma unroll
    for (int o = 32; o > 0; o >>= 1) p += __shfl_down(p, o, 64);
    if (lane == 0) out[w] = p * (1.0f / 16.0f);
}

// ---------------------------------------------------------------------------
extern "C" void kernel_launch(void* const* d_in, const int* in_sizes, int n_in,
                              void* d_out, int out_size, void* d_ws, size_t ws_size,
                              hipStream_t stream) {
    const int*   users = (const int*)  d_in[0];
    const int*   items = (const int*)  d_in[1];
    const int*   erow  = (const int*)  d_in[2];
    const int*   ecol  = (const int*)  d_in[3];
    const float* evalv = (const float*)d_in[4];
    const float* ue    = (const float*)d_in[5];
    const float* ie    = (const float*)d_in[6];
    float* out = (float*)d_out;

    // workspace layout
    float* emb_a     = (float*)d_ws;                      // ND floats
    float* emb_b     = emb_a + ND;                        // ND floats
    float* acc_small = emb_b + ND;                        // NSAMP*DIM floats
    int2*  csr       = (int2*)(acc_small + NSAMP * DIM);  // N_EDGES int2
    int*   counts    = (int*)(csr + N_EDGES);             // N_NODES
    int*   offsets   = counts + N_NODES;                  // N_NODES+1
    int*   blocksums = offsets + N_NODES + 1;             // <=1024
    unsigned char* mask3 = (unsigned char*)(blocksums + 1024); // N_NODES
    unsigned char* mask2 = mask3 + N_NODES;
    unsigned char* mask1 = mask2 + N_NODES;

    const int block = 256;
    const int nscan_blocks = (N_NODES + 255) / 256;       // 586
    const int grid_nodes = (N_NODES + 255) / 256;
    const int grid_edges = 2048;
    const int spmm_blocks = (N_NODES + 3) / 4;            // 4 waves/block
    const int samp_blocks = (NSAMP * 64 + block - 1) / block;

    // --- zero counters & masks -------------------------------------------
    hipMemsetAsync(counts, 0, (size_t)N_NODES * sizeof(int), stream);
    hipMemsetAsync(mask3, 0, (size_t)3 * N_NODES, stream);

    // --- build CSR --------------------------------------------------------
    hist_kernel<<<grid_edges, block, 0, stream>>>(erow, counts);
    scan_block_kernel<<<nscan_blocks, 256, 0, stream>>>(counts, offsets, blocksums, N_NODES);
    scan_sums_kernel<<<1, 1024, 0, stream>>>(blocksums, nscan_blocks);
    add_offsets_kernel<<<nscan_blocks, 256, 0, stream>>>(offsets, blocksums, N_NODES);
    fill_kernel<<<grid_edges, block, 0, stream>>>(erow, ecol, evalv, offsets, counts, csr);

    // --- frontier masks ---------------------------------------------------
    mark_s_kernel<<<(NSAMP + block - 1) / block, block, 0, stream>>>(users, items, mask3);
    copy_mask_kernel<<<grid_nodes, block, 0, stream>>>(mask3, mask2);
    expand_kernel<<<grid_edges, block, 0, stream>>>(erow, ecol, mask3, mask2);
    copy_mask_kernel<<<grid_nodes, block, 0, stream>>>(mask2, mask1);
    expand_kernel<<<grid_edges, block, 0, stream>>>(erow, ecol, mask2, mask1);

    // --- layer 0 contribution (raw tables, translated) --------------------
    accum_kernel<true><<<samp_blocks, block, 0, stream>>>(users, items, nullptr,
                                                          ue, ie, acc_small);

    // --- 3 propagation layers ---------------------------------------------
    spmm_kernel<true><<<spmm_blocks, block, 0, stream>>>(offsets, csr, nullptr,
                                                         ue, ie, mask1, emb_a);
    accum_kernel<false><<<samp_blocks, block, 0, stream>>>(users, items, emb_a,
                                                           nullptr, nullptr, acc_small);

    spmm_kernel<false><<<spmm_blocks, block, 0, stream>>>(offsets, csr, emb_a,
                                                          nullptr, nullptr, mask2, emb_b);
    accum_kernel<false><<<samp_blocks, block, 0, stream>>>(users, items, emb_b,
                                                           nullptr, nullptr, acc_small);

    spmm_kernel<false><<<spmm_blocks, block, 0, stream>>>(offsets, csr, emb_b,
                                                          nullptr, nullptr, mask3, emb_a);
    accum_kernel<false><<<samp_blocks, block, 0, stream>>>(users, items, emb_a,
                                                           nullptr, nullptr, acc_small);

    // --- final dot ---------------------------------------------------------
    dot_kernel<<<(NB * 64 + block - 1) / block, block, 0, stream>>>(acc_small, out);
}

// Round 4
// 266.700 us; speedup vs baseline: 3.6076x; 1.4831x over previous
//
#include <hip/hip_runtime.h>

// LightGCN propagation — ELL format + fused dispatch chain (7 dispatches).
//  - ELL (W=28) built in ONE kernel (atomicAdd slot alloc); no scan chain.
//    Overflow rows (deg>28, P~1e-3) spill to a tiny COO list checked by spmm.
//  - spmm: 4 rows per wave, 16 lanes x float4 per row -> 8 outstanding
//    gathers/wave (latency-bound fix).
//  - accum of layer L fused into spmm of layer L+1 (extra blocks); final
//    accum fused into dot. mask1 dropped (3% pruning not worth a dispatch).

#define NUM_USERS 100000
#define NUM_ITEMS 50000
#define N_NODES   150000
#define DIM       64
#define N_EDGES   1200000
#define ND        (N_NODES * DIM)
#define NB        4096
#define NSAMP     (2 * NB)
#define ELL_W     28
#define OVF_CAP   512

#define FILL_BLOCKS 2048
#define MARK_BLOCKS 32            // 32*256 = 8192 = NSAMP
#define EXP_BLOCKS  2048
#define CPY_BLOCKS  586           // 586*256 >= N_NODES
#define SPMM_BLOCKS 9375          // 16 rows/block * 9375 = 150000
#define ACC_BLOCKS  512           // 16 slots/block * 512 = 8192

__device__ __forceinline__ float4 f4fma(float v, float4 x, float4 a) {
    a.x += v * x.x; a.y += v * x.y; a.z += v * x.z; a.w += v * x.w;
    return a;
}

// source row pointer: FIRST layer reads raw tables, later layers read emb
template<bool FIRST>
__device__ __forceinline__ const float* srcp(const float* __restrict__ x,
                                             const float* __restrict__ ue,
                                             const float* __restrict__ ie,
                                             int node) {
    if (FIRST)
        return (node < NUM_USERS) ? ue + node * DIM
                                  : ie + (node - NUM_USERS) * DIM;
    return x + node * DIM;
}

// ---------------------------------------------------------------------------
// fill ELL (+ inline histogram) and mark mask3 (sampled nodes), fused.
// ---------------------------------------------------------------------------
__global__ void fill_mark_kernel(const int* __restrict__ erow,
                                 const int* __restrict__ ecol,
                                 const float* __restrict__ evalv,
                                 const int* __restrict__ users,
                                 const int* __restrict__ items,
                                 int* __restrict__ counts,
                                 int2* __restrict__ ell,
                                 int4* __restrict__ ovf,
                                 int* __restrict__ ovf_cnt,
                                 unsigned char* __restrict__ mask3) {
    if (blockIdx.x < FILL_BLOCKS) {
        int i = blockIdx.x * 256 + threadIdx.x;
        const int stride = FILL_BLOCKS * 256;
        for (; i < N_EDGES; i += stride) {
            int r = erow[i];
            int slot = atomicAdd(&counts[r], 1);
            if (slot < ELL_W) {
                ell[r * ELL_W + slot] = make_int2(ecol[i], __float_as_int(evalv[i]));
            } else {
                int p = atomicAdd(ovf_cnt, 1);
                if (p < OVF_CAP)
                    ovf[p] = make_int4(r, ecol[i], __float_as_int(evalv[i]), 0);
            }
        }
    } else {
        int i = (blockIdx.x - FILL_BLOCKS) * 256 + threadIdx.x;
        if (i < NB)          mask3[users[i]] = 1;
        else if (i < NSAMP)  mask3[NUM_USERS + items[i - NB]] = 1;
    }
}

// ---------------------------------------------------------------------------
// mask2 = mask3 | cols(rows in mask3)   (copy + edge expand in one kernel)
// ---------------------------------------------------------------------------
__global__ void expand_kernel(const int* __restrict__ erow,
                              const int* __restrict__ ecol,
                              const unsigned char* __restrict__ mIn,
                              unsigned char* __restrict__ mOut) {
    if (blockIdx.x < EXP_BLOCKS) {
        int i = blockIdx.x * 256 + threadIdx.x;
        const int stride = EXP_BLOCKS * 256;
        for (; i < N_EDGES; i += stride)
            if (mIn[erow[i]]) mOut[ecol[i]] = 1;
    } else {
        int i = (blockIdx.x - EXP_BLOCKS) * 256 + threadIdx.x;
        if (i < N_NODES && mIn[i]) mOut[i] = 1;
    }
}

// ---------------------------------------------------------------------------
// fused spmm + blend (+ accum of the INPUT layer at sampled slots).
//   wave = 4 rows (16 lanes each, float4 dims)
//   out[row] = 0.2*x[row] + 0.8 * sum_e val[e]*x[col[e]]
// ---------------------------------------------------------------------------
template<bool FIRST, bool MASKED, bool ACC_STORE>
__global__ void spmm_kernel(const int* __restrict__ counts,
                            const int2* __restrict__ ell,
                            const float* __restrict__ x,
                            const float* __restrict__ ue,
                            const float* __restrict__ ie,
                            const unsigned char* __restrict__ mask,
                            const int* __restrict__ ovf_cnt,
                            const int4* __restrict__ ovf,
                            const int* __restrict__ users,
                            const int* __restrict__ items,
                            float* __restrict__ acc_small,
                            float* __restrict__ xout) {
    const int wid  = threadIdx.x >> 6;   // wave in block: 0..3
    const int lane = threadIdx.x & 63;
    const int g    = lane >> 4;          // row group within wave: 0..3
    const int t    = lane & 15;          // dim quad: dims 4t..4t+3

    if (blockIdx.x < SPMM_BLOCKS) {
        const int row = blockIdx.x * 16 + wid * 4 + g;   // < 150000 always
        bool active = true;
        if (MASKED) active = mask[row] != 0;
        int cnt = 0;
        if (active) {
            cnt = counts[row];
            cnt = cnt < ELL_W ? cnt : ELL_W;
        }
        const int2* ep = ell + row * ELL_W;
        float4 a0 = {0, 0, 0, 0}, a1 = {0, 0, 0, 0};
        int j = 0;
        for (; j + 2 <= cnt; j += 2) {
            int4 cv = *(const int4*)(ep + j);   // {c0,v0,c1,v1}, 16B aligned
            const float* p0 = srcp<FIRST>(x, ue, ie, cv.x);
            const float* p1 = srcp<FIRST>(x, ue, ie, cv.z);
            float4 x0 = *(const float4*)(p0 + t * 4);
            float4 x1 = *(const float4*)(p1 + t * 4);
            a0 = f4fma(__int_as_float(cv.y), x0, a0);
            a1 = f4fma(__int_as_float(cv.w), x1, a1);
        }
        if (j < cnt) {
            int2 cv = ep[j];
            const float* p = srcp<FIRST>(x, ue, ie, cv.x);
            float4 xv = *(const float4*)(p + t * 4);
            a0 = f4fma(__int_as_float(cv.y), xv, a0);
        }
        // overflow edges (normally zero)
        int novf = *ovf_cnt;
        if (novf > 0) {
            novf = novf < OVF_CAP ? novf : OVF_CAP;
            for (int k = 0; k < novf; ++k) {
                int4 o = ovf[k];
                if (active && o.x == row) {
                    const float* p = srcp<FIRST>(x, ue, ie, o.y);
                    float4 xv = *(const float4*)(p + t * 4);
                    a0 = f4fma(__int_as_float(o.z), xv, a0);
                }
            }
        }
        if (active) {
            const float* ps = srcp<FIRST>(x, ue, ie, row);
            float4 self = *(const float4*)(ps + t * 4);
            float4 r;
            r.x = 0.2f * self.x + 0.8f * (a0.x + a1.x);
            r.y = 0.2f * self.y + 0.8f * (a0.y + a1.y);
            r.z = 0.2f * self.z + 0.8f * (a0.z + a1.z);
            r.w = 0.2f * self.w + 0.8f * (a0.w + a1.w);
            *(float4*)(xout + row * DIM + t * 4) = r;
        }
    } else {
        // accum of the INPUT layer at sampled slots (16 slots/block)
        const int s = (blockIdx.x - SPMM_BLOCKS) * 16 + wid * 4 + g;  // < 8192
        const int node = (s < NB) ? users[s] : (NUM_USERS + items[s - NB]);
        const float* p = srcp<FIRST>(x, ue, ie, node);
        float4 v = *(const float4*)(p + t * 4);
        float4* ap = (float4*)(acc_small + s * DIM + t * 4);
        if (ACC_STORE) {
            *ap = v;
        } else {
            float4 a = *ap;
            a.x += v.x; a.y += v.y; a.z += v.z; a.w += v.w;
            *ap = a;
        }
    }
}

// ---------------------------------------------------------------------------
// out[b] = dot(acc[b] + e3[u], acc[NB+b] + e3[i]) / 16   (layer-3 fused)
// ---------------------------------------------------------------------------
__global__ void dot_kernel(const int* __restrict__ users,
                           const int* __restrict__ items,
                           const float* __restrict__ acc_small,
                           const float* __restrict__ emb3,
                           float* __restrict__ out) {
    int w = (blockIdx.x * blockDim.x + threadIdx.x) >> 6;
    int lane = threadIdx.x & 63;
    if (w >= NB) return;
    int u  = users[w];
    int it = items[w];
    float au = acc_small[w * DIM + lane]        + emb3[u * DIM + lane];
    float ai = acc_small[(NB + w) * DIM + lane] + emb3[(NUM_USERS + it) * DIM + lane];
    float p = au * ai;
    #pragma unroll
    for (int o = 32; o > 0; o >>= 1) p += __shfl_down(p, o, 64);
    if (lane == 0) out[w] = p * (1.0f / 16.0f);
}

// ---------------------------------------------------------------------------
extern "C" void kernel_launch(void* const* d_in, const int* in_sizes, int n_in,
                              void* d_out, int out_size, void* d_ws, size_t ws_size,
                              hipStream_t stream) {
    const int*   users = (const int*)  d_in[0];
    const int*   items = (const int*)  d_in[1];
    const int*   erow  = (const int*)  d_in[2];
    const int*   ecol  = (const int*)  d_in[3];
    const float* evalv = (const float*)d_in[4];
    const float* ue    = (const float*)d_in[5];
    const float* ie    = (const float*)d_in[6];
    float* out = (float*)d_out;

    // workspace layout (~113.4 MB total)
    float* emb_a     = (float*)d_ws;                       // ND floats
    float* emb_b     = emb_a + ND;                         // ND floats
    float* acc_small = emb_b + ND;                         // NSAMP*DIM floats
    int2*  ell       = (int2*)(acc_small + NSAMP * DIM);   // N_NODES*ELL_W int2
    int*   counts    = (int*)(ell + (size_t)N_NODES * ELL_W); // N_NODES ints
    unsigned char* mask3 = (unsigned char*)(counts + N_NODES); // N_NODES
    unsigned char* mask2 = mask3 + N_NODES;                    // N_NODES
    int4*  ovf       = (int4*)(mask2 + N_NODES);           // OVF_CAP (16B-aligned)
    int*   ovf_cnt   = (int*)(ovf + OVF_CAP);              // 1 int

    const int block = 256;

    // one memset covers counts | mask3 | mask2 | ovf | ovf_cnt (contiguous)
    size_t zbytes = (char*)(ovf_cnt + 1) - (char*)counts;
    hipMemsetAsync(counts, 0, zbytes, stream);

    // build ELL + mark sampled nodes
    fill_mark_kernel<<<FILL_BLOCKS + MARK_BLOCKS, block, 0, stream>>>(
        erow, ecol, evalv, users, items, counts, ell, ovf, ovf_cnt, mask3);

    // mask2 = mask3 | in-neighbors(mask3)
    expand_kernel<<<EXP_BLOCKS + CPY_BLOCKS, block, 0, stream>>>(
        erow, ecol, mask3, mask2);

    // layer 1 (unmasked, reads raw tables) + acc0(store)
    spmm_kernel<true, false, true><<<SPMM_BLOCKS + ACC_BLOCKS, block, 0, stream>>>(
        counts, ell, nullptr, ue, ie, nullptr, ovf_cnt, ovf,
        users, items, acc_small, emb_a);

    // layer 2 (mask2) + acc1
    spmm_kernel<false, true, false><<<SPMM_BLOCKS + ACC_BLOCKS, block, 0, stream>>>(
        counts, ell, emb_a, nullptr, nullptr, mask2, ovf_cnt, ovf,
        users, items, acc_small, emb_b);

    // layer 3 (mask3) + acc2
    spmm_kernel<false, true, false><<<SPMM_BLOCKS + ACC_BLOCKS, block, 0, stream>>>(
        counts, ell, emb_b, nullptr, nullptr, mask3, ovf_cnt, ovf,
        users, items, acc_small, emb_a);

    // dot with layer-3 accum fused
    dot_kernel<<<(NB * 64 + block - 1) / block, block, 0, stream>>>(
        users, items, acc_small, emb_a, out);
}

// Round 5
// 251.831 us; speedup vs baseline: 3.8206x; 1.0590x over previous
//
#include <hip/hip_runtime.h>
#include <stdint.h>

// LightGCN propagation — bucketed counting-sort ELL build + fused chain.
//  - K1: edges appended to 1000x8 XCD-affine sub-buckets (blockIdx&7), int4
//    vectorized edge reads, 4 atomics+stores in flight. Mark blocks ride along.
//  - K2: one block per bucket builds 150x24 ELL slice in LDS, writes out
//    fully coalesced. Expand/copy blocks ride along.
//  - spmm: 4 rows/wave, 16 lanes x float4, 4-edge unroll (4 gathers in flight),
//    accum of the input layer fused as extra blocks; final accum fused in dot.

#define NUM_USERS 100000
#define NUM_ITEMS 50000
#define N_NODES   150000
#define DIM       64
#define N_EDGES   1200000
#define ND        (N_NODES * DIM)
#define NB        4096
#define NSAMP     (2 * NB)

#define ELL_W     24
#define RPB       150               // rows per bucket
#define NBKT      1000              // NBKT*RPB == N_NODES
#define NSUB      8                 // sub-buckets (XCD heuristic)
#define SUB_CAP   256               // records per sub-bucket (mean 150, +8.7 sigma)
#define OVF_CAP   1024

#define K1_EDGE_BLOCKS 1024
#define K1_MARK_BLOCKS 32           // 32*256 == NSAMP
#define K2_EXP_BLOCKS  2048
#define K2_CPY_BLOCKS  586
#define SPMM_BLOCKS    9375         // 16 rows/block
#define ACC_BLOCKS     512          // 16 slots/block

__device__ __forceinline__ float4 f4fma(float v, float4 x, float4 a) {
    a.x += v * x.x; a.y += v * x.y; a.z += v * x.z; a.w += v * x.w;
    return a;
}

template<bool FIRST>
__device__ __forceinline__ const float* srcp(const float* __restrict__ x,
                                             const float* __restrict__ ue,
                                             const float* __restrict__ ie,
                                             int node) {
    if (FIRST)
        return (node < NUM_USERS) ? ue + node * DIM
                                  : ie + (node - NUM_USERS) * DIM;
    return x + node * DIM;
}

// ---------------------------------------------------------------------------
// K1: bucket-append (XCD-affine sub-buckets) + mark sampled nodes
// ---------------------------------------------------------------------------
__global__ void k1_bucket_mark(const int* __restrict__ erow,
                               const int* __restrict__ ecol,
                               const float* __restrict__ evalv,
                               const int* __restrict__ users,
                               const int* __restrict__ items,
                               int* __restrict__ btails,
                               int4* __restrict__ buckets,
                               int4* __restrict__ ovf,
                               int* __restrict__ ovf_cnt,
                               unsigned char* __restrict__ mask3) {
    if (blockIdx.x < K1_EDGE_BLOCKS) {
        const int sub = blockIdx.x & (NSUB - 1);
        int base = (blockIdx.x * 256 + threadIdx.x) * 4;
        const int stride = K1_EDGE_BLOCKS * 256 * 4;
        for (; base < N_EDGES; base += stride) {      // N_EDGES % 4 == 0
            int4   r4 = *(const int4*)(erow + base);
            int4   c4 = *(const int4*)(ecol + base);
            float4 v4 = *(const float4*)(evalv + base);
            int b0 = r4.x / RPB, b1 = r4.y / RPB, b2 = r4.z / RPB, b3 = r4.w / RPB;
            int p0 = atomicAdd(&btails[b0 * NSUB + sub], 1);
            int p1 = atomicAdd(&btails[b1 * NSUB + sub], 1);
            int p2 = atomicAdd(&btails[b2 * NSUB + sub], 1);
            int p3 = atomicAdd(&btails[b3 * NSUB + sub], 1);
            // record = {col, val_bits, row_local, 0}
            if (p0 < SUB_CAP)
                buckets[(size_t)(b0 * NSUB + sub) * SUB_CAP + p0] =
                    make_int4(c4.x, __float_as_int(v4.x), r4.x - b0 * RPB, 0);
            else { int q = atomicAdd(ovf_cnt, 1);
                   if (q < OVF_CAP) ovf[q] = make_int4(r4.x, c4.x, __float_as_int(v4.x), 0); }
            if (p1 < SUB_CAP)
                buckets[(size_t)(b1 * NSUB + sub) * SUB_CAP + p1] =
                    make_int4(c4.y, __float_as_int(v4.y), r4.y - b1 * RPB, 0);
            else { int q = atomicAdd(ovf_cnt, 1);
                   if (q < OVF_CAP) ovf[q] = make_int4(r4.y, c4.y, __float_as_int(v4.y), 0); }
            if (p2 < SUB_CAP)
                buckets[(size_t)(b2 * NSUB + sub) * SUB_CAP + p2] =
                    make_int4(c4.z, __float_as_int(v4.z), r4.z - b2 * RPB, 0);
            else { int q = atomicAdd(ovf_cnt, 1);
                   if (q < OVF_CAP) ovf[q] = make_int4(r4.z, c4.z, __float_as_int(v4.z), 0); }
            if (p3 < SUB_CAP)
                buckets[(size_t)(b3 * NSUB + sub) * SUB_CAP + p3] =
                    make_int4(c4.w, __float_as_int(v4.w), r4.w - b3 * RPB, 0);
            else { int q = atomicAdd(ovf_cnt, 1);
                   if (q < OVF_CAP) ovf[q] = make_int4(r4.w, c4.w, __float_as_int(v4.w), 0); }
        }
    } else {
        int i = (blockIdx.x - K1_EDGE_BLOCKS) * 256 + threadIdx.x;
        if (i < NB)         mask3[users[i]] = 1;
        else if (i < NSAMP) mask3[NUM_USERS + items[i - NB]] = 1;
    }
}

// ---------------------------------------------------------------------------
// K2: per-bucket ELL build in LDS (coalesced write-out) + mask expand/copy
// ---------------------------------------------------------------------------
__global__ __launch_bounds__(256)
void k2_ell_expand(const int* __restrict__ erow,
                   const int* __restrict__ ecol,
                   const int* __restrict__ btails,
                   const int4* __restrict__ buckets,
                   int* __restrict__ counts,
                   int2* __restrict__ ell,
                   int4* __restrict__ ovf,
                   int* __restrict__ ovf_cnt,
                   const unsigned char* __restrict__ mask3,
                   unsigned char* __restrict__ mask2) {
    __shared__ __align__(16) int2 lell[RPB * ELL_W];   // 28.8 KB
    __shared__ int lcnt[RPB];
    if (blockIdx.x < NBKT) {
        const int bkt   = blockIdx.x;
        const int rbase = bkt * RPB;
        for (int k = threadIdx.x; k < RPB; k += 256) lcnt[k] = 0;
        __syncthreads();
        const int wid = threadIdx.x >> 6, lane = threadIdx.x & 63;
        for (int s = wid * 2; s < wid * 2 + 2; ++s) {   // 4 waves x 2 subs
            int n = btails[bkt * NSUB + s];
            n = n < SUB_CAP ? n : SUB_CAP;
            const int4* bp = buckets + (size_t)(bkt * NSUB + s) * SUB_CAP;
            for (int e = lane; e < n; e += 64) {
                int4 rec = bp[e];
                int slot = atomicAdd(&lcnt[rec.z], 1);
                if (slot < ELL_W)
                    lell[rec.z * ELL_W + slot] = make_int2(rec.x, rec.y);
                else { int q = atomicAdd(ovf_cnt, 1);
                       if (q < OVF_CAP) ovf[q] = make_int4(rbase + rec.z, rec.x, rec.y, 0); }
            }
        }
        __syncthreads();
        int4* gell4 = (int4*)(ell + (size_t)rbase * ELL_W);
        const int4* lell4 = (const int4*)lell;
        for (int k = threadIdx.x; k < RPB * ELL_W / 2; k += 256) gell4[k] = lell4[k];
        for (int k = threadIdx.x; k < RPB; k += 256) counts[rbase + k] = lcnt[k];
    } else if (blockIdx.x < NBKT + K2_EXP_BLOCKS) {
        int i = (blockIdx.x - NBKT) * 256 + threadIdx.x;
        const int stride = K2_EXP_BLOCKS * 256;
        for (; i < N_EDGES; i += stride)
            if (mask3[erow[i]]) mask2[ecol[i]] = 1;
    } else {
        int i = (blockIdx.x - NBKT - K2_EXP_BLOCKS) * 256 + threadIdx.x;
        if (i < N_NODES && mask3[i]) mask2[i] = 1;
    }
}

// ---------------------------------------------------------------------------
// fused spmm + blend (+ accum of the INPUT layer at sampled slots)
//   wave = 4 rows (16 lanes each, float4 dims); 4-edge unroll
// ---------------------------------------------------------------------------
template<bool FIRST, bool MASKED, bool ACC_STORE>
__global__ void spmm_kernel(const int* __restrict__ counts,
                            const int2* __restrict__ ell,
                            const float* __restrict__ x,
                            const float* __restrict__ ue,
                            const float* __restrict__ ie,
                            const unsigned char* __restrict__ mask,
                            const int* __restrict__ ovf_cnt,
                            const int4* __restrict__ ovf,
                            const int* __restrict__ users,
                            const int* __restrict__ items,
                            float* __restrict__ acc_small,
                            float* __restrict__ xout) {
    const int wid  = threadIdx.x >> 6;
    const int lane = threadIdx.x & 63;
    const int g    = lane >> 4;
    const int t    = lane & 15;

    if (blockIdx.x < SPMM_BLOCKS) {
        const int row = blockIdx.x * 16 + wid * 4 + g;
        bool active = true;
        if (MASKED) active = mask[row] != 0;
        int cnt = 0;
        if (active) {
            cnt = counts[row];
            cnt = cnt < ELL_W ? cnt : ELL_W;
        }
        const int2* ep = ell + (size_t)row * ELL_W;
        float4 a0 = {0,0,0,0}, a1 = {0,0,0,0}, a2 = {0,0,0,0}, a3 = {0,0,0,0};
        int j = 0;
        for (; j + 4 <= cnt; j += 4) {
            int4 cv0 = *(const int4*)(ep + j);
            int4 cv1 = *(const int4*)(ep + j + 2);
            const float* p0 = srcp<FIRST>(x, ue, ie, cv0.x);
            const float* p1 = srcp<FIRST>(x, ue, ie, cv0.z);
            const float* p2 = srcp<FIRST>(x, ue, ie, cv1.x);
            const float* p3 = srcp<FIRST>(x, ue, ie, cv1.z);
            float4 x0 = *(const float4*)(p0 + t * 4);
            float4 x1 = *(const float4*)(p1 + t * 4);
            float4 x2 = *(const float4*)(p2 + t * 4);
            float4 x3 = *(const float4*)(p3 + t * 4);
            a0 = f4fma(__int_as_float(cv0.y), x0, a0);
            a1 = f4fma(__int_as_float(cv0.w), x1, a1);
            a2 = f4fma(__int_as_float(cv1.y), x2, a2);
            a3 = f4fma(__int_as_float(cv1.w), x3, a3);
        }
        for (; j + 2 <= cnt; j += 2) {
            int4 cv = *(const int4*)(ep + j);
            const float* p0 = srcp<FIRST>(x, ue, ie, cv.x);
            const float* p1 = srcp<FIRST>(x, ue, ie, cv.z);
            float4 x0 = *(const float4*)(p0 + t * 4);
            float4 x1 = *(const float4*)(p1 + t * 4);
            a0 = f4fma(__int_as_float(cv.y), x0, a0);
            a1 = f4fma(__int_as_float(cv.w), x1, a1);
        }
        if (j < cnt) {
            int2 cv = ep[j];
            const float* p = srcp<FIRST>(x, ue, ie, cv.x);
            float4 xv = *(const float4*)(p + t * 4);
            a0 = f4fma(__int_as_float(cv.y), xv, a0);
        }
        int novf = *ovf_cnt;
        if (novf > 0) {
            novf = novf < OVF_CAP ? novf : OVF_CAP;
            for (int k = 0; k < novf; ++k) {
                int4 o = ovf[k];
                if (active && o.x == row) {
                    const float* p = srcp<FIRST>(x, ue, ie, o.y);
                    float4 xv = *(const float4*)(p + t * 4);
                    a0 = f4fma(__int_as_float(o.z), xv, a0);
                }
            }
        }
        if (active) {
            const float* ps = srcp<FIRST>(x, ue, ie, row);
            float4 self = *(const float4*)(ps + t * 4);
            float4 r;
            r.x = 0.2f * self.x + 0.8f * ((a0.x + a1.x) + (a2.x + a3.x));
            r.y = 0.2f * self.y + 0.8f * ((a0.y + a1.y) + (a2.y + a3.y));
            r.z = 0.2f * self.z + 0.8f * ((a0.z + a1.z) + (a2.z + a3.z));
            r.w = 0.2f * self.w + 0.8f * ((a0.w + a1.w) + (a2.w + a3.w));
            *(float4*)(xout + (size_t)row * DIM + t * 4) = r;
        }
    } else {
        const int s = (blockIdx.x - SPMM_BLOCKS) * 16 + wid * 4 + g;
        const int node = (s < NB) ? users[s] : (NUM_USERS + items[s - NB]);
        const float* p = srcp<FIRST>(x, ue, ie, node);
        float4 v = *(const float4*)(p + t * 4);
        float4* ap = (float4*)(acc_small + (size_t)s * DIM + t * 4);
        if (ACC_STORE) {
            *ap = v;
        } else {
            float4 a = *ap;
            a.x += v.x; a.y += v.y; a.z += v.z; a.w += v.w;
            *ap = a;
        }
    }
}

// ---------------------------------------------------------------------------
// out[b] = dot(acc[b] + e3[u], acc[NB+b] + e3[i]) / 16   (layer-3 accum fused)
// ---------------------------------------------------------------------------
__global__ void dot_kernel(const int* __restrict__ users,
                           const int* __restrict__ items,
                           const float* __restrict__ acc_small,
                           const float* __restrict__ emb3,
                           float* __restrict__ out) {
    int w = (blockIdx.x * blockDim.x + threadIdx.x) >> 6;
    int lane = threadIdx.x & 63;
    if (w >= NB) return;
    int u  = users[w];
    int it = items[w];
    float au = acc_small[w * DIM + lane]        + emb3[(size_t)u * DIM + lane];
    float ai = acc_small[(NB + w) * DIM + lane] + emb3[(size_t)(NUM_USERS + it) * DIM + lane];
    float p = au * ai;
    #pragma unroll
    for (int o = 32; o > 0; o >>= 1) p += __shfl_down(p, o, 64);
    if (lane == 0) out[w] = p * (1.0f / 16.0f);
}

// ---------------------------------------------------------------------------
extern "C" void kernel_launch(void* const* d_in, const int* in_sizes, int n_in,
                              void* d_out, int out_size, void* d_ws, size_t ws_size,
                              hipStream_t stream) {
    const int*   users = (const int*)  d_in[0];
    const int*   items = (const int*)  d_in[1];
    const int*   erow  = (const int*)  d_in[2];
    const int*   ecol  = (const int*)  d_in[3];
    const float* evalv = (const float*)d_in[4];
    const float* ue    = (const float*)d_in[5];
    const float* ie    = (const float*)d_in[6];
    float* out = (float*)d_out;

    // workspace layout (~108.6 MB)
    float* emb_a     = (float*)d_ws;                          // ND floats
    float* emb_b     = emb_a + ND;                            // ND floats
    int4*  buckets   = (int4*)emb_b;                          // alias: 32.8 MB <= 38.4 MB
    float* acc_small = emb_b + ND;                            // NSAMP*DIM floats
    int2*  ell       = (int2*)(acc_small + NSAMP * DIM);      // N_NODES*ELL_W int2
    int*   counts    = (int*)(ell + (size_t)N_NODES * ELL_W); // N_NODES (no memset needed)
    int*   btails    = counts + N_NODES;                      // NBKT*NSUB
    int*   ovf_cnt   = btails + NBKT * NSUB;                  // 1
    int4*  ovf       = (int4*)(((uintptr_t)(ovf_cnt + 1) + 15) & ~(uintptr_t)15);
    unsigned char* mask3 = (unsigned char*)(ovf + OVF_CAP);   // N_NODES
    unsigned char* mask2 = mask3 + N_NODES;                   // N_NODES

    const int block = 256;

    // zero btails | ovf_cnt | ovf | mask3 | mask2 (contiguous, ~350 KB)
    size_t zbytes = (size_t)((mask2 + N_NODES) - (unsigned char*)btails);
    hipMemsetAsync(btails, 0, zbytes, stream);

    k1_bucket_mark<<<K1_EDGE_BLOCKS + K1_MARK_BLOCKS, block, 0, stream>>>(
        erow, ecol, evalv, users, items, btails, buckets, ovf, ovf_cnt, mask3);

    k2_ell_expand<<<NBKT + K2_EXP_BLOCKS + K2_CPY_BLOCKS, block, 0, stream>>>(
        erow, ecol, btails, buckets, counts, ell, ovf, ovf_cnt, mask3, mask2);

    // layer 1 (unmasked, reads raw tables) + acc0(store)
    spmm_kernel<true, false, true><<<SPMM_BLOCKS + ACC_BLOCKS, block, 0, stream>>>(
        counts, ell, nullptr, ue, ie, nullptr, ovf_cnt, ovf,
        users, items, acc_small, emb_a);

    // layer 2 (mask2) + acc1
    spmm_kernel<false, true, false><<<SPMM_BLOCKS + ACC_BLOCKS, block, 0, stream>>>(
        counts, ell, emb_a, nullptr, nullptr, mask2, ovf_cnt, ovf,
        users, items, acc_small, emb_b);

    // layer 3 (mask3) + acc2
    spmm_kernel<false, true, false><<<SPMM_BLOCKS + ACC_BLOCKS, block, 0, stream>>>(
        counts, ell, emb_b, nullptr, nullptr, mask3, ovf_cnt, ovf,
        users, items, acc_small, emb_a);

    // dot with layer-3 accum fused
    dot_kernel<<<(NB * 64 + block - 1) / block, block, 0, stream>>>(
        users, items, acc_small, emb_a, out);
}